// Round 3
// baseline (1015.372 us; speedup 1.0000x reference)
//
#include <hip/hip_runtime.h>
#include <math.h>

// ---------------- problem constants ----------------
#define BB 16
#define CIN 15
#define HW 384
#define XPL 147456             // 384*384
#define PH 96
#define GW 192
#define WP 392                 // padded width (3 halo each side, +2 slack)
#define IPL 153664             // 392*392
#define YP 98                  // padded Y1 spatial
#define Y1IPL (98*98*64)       // 614656 elems per image
#define OUT_ELEMS (BB*6*PH*PH)

// ws byte offsets (peak 76,463,104 B <= proven-available 77,594,624 B)
#define OFF_WG   0             // [64][960] bf16 (BN-folded)
#define OFF_WE1  122880        // [3][64][960] bf16
#define OFF_WH   491520        // [3][384][576] bf16 (k=kk*64+ic)
#define OFF_GSH  1818624      // fp32 [64]
#define OFF_FEAT 1818880      // fp32 [16][64]
#define OFF_IDX  1822976      // int  [16]
#define OFF_XPAD 1835008      // bf16 [8][15][392][392] = 36,879,360 B (half batch)
#define OFF_CBUF 38714368     // bf16 [8][192][192][64] = 37,748,736 B; Y1 overlays

typedef __attribute__((ext_vector_type(8))) short short8;
typedef __attribute__((ext_vector_type(4))) float floatx4;
typedef __attribute__((ext_vector_type(4))) unsigned int uintx4;
typedef __attribute__((ext_vector_type(2))) unsigned int uintx2;

__device__ __forceinline__ unsigned bf16rne(float f) {
  unsigned u = __float_as_uint(f);
  unsigned r = ((u >> 16) & 1u) + 0x7FFFu;
  return (u + r) >> 16;
}
__device__ __forceinline__ float bf2f(unsigned short s) {
  return __uint_as_float(((unsigned)s) << 16);
}

// ---------------- K0: weight prep ----------------
// Wg: [oc][k960], k = ic*64+ky*8+kx, BN-folded (ky=7,kx=7 -> 0). We1: [e][oc][k960].
// Wh: [e][oc][k576], k = (ky*3+kx)*64+ic. gsh: BN shift.
__global__ __launch_bounds__(256) void k_prep(
    const float* __restrict__ g_conv_w, const float* __restrict__ e_conv1_w,
    const float* __restrict__ e_head_w1,
    const float* __restrict__ gamma, const float* __restrict__ var,
    const float* __restrict__ beta,  const float* __restrict__ mean,
    unsigned char* __restrict__ wsb)
{
  int i = blockIdx.x * 256 + threadIdx.x;
  unsigned short* Wg  = (unsigned short*)(wsb + OFF_WG);
  unsigned short* We1 = (unsigned short*)(wsb + OFF_WE1);
  unsigned short* Wh  = (unsigned short*)(wsb + OFF_WH);
  float* gsh = (float*)(wsb + OFF_GSH);
  if (i < 61440) {
    int oc = i / 960, k = i % 960;
    int ic = k >> 6, rem = k & 63, ky = rem >> 3, kx = rem & 7;
    float v = 0.f;
    if (ky < 7 && kx < 7) v = g_conv_w[oc * 735 + ic * 49 + ky * 7 + kx];
    float inv = gamma[oc] * rsqrtf(var[oc] + 1e-5f);
    Wg[i] = (unsigned short)bf16rne(v * inv);
  } else if (i < 245760) {
    int j = i - 61440;
    int e = j / 61440, r = j % 61440;
    int oc = r / 960, k = r % 960;
    int ic = k >> 6, rem = k & 63, ky = rem >> 3, kx = rem & 7;
    float v = 0.f;
    if (ky < 7 && kx < 7) v = e_conv1_w[(e * 64 + oc) * 735 + ic * 49 + ky * 7 + kx];
    We1[j] = (unsigned short)bf16rne(v);
  } else if (i < 909312) {
    int j = i - 245760;
    int e = j / 221184, r = j % 221184;
    int oc = r / 576, k = r % 576;
    int kk = k >> 6, ic = k & 63;
    float v = e_head_w1[((e * 384 + oc) * 64 + ic) * 9 + kk];
    Wh[j] = (unsigned short)bf16rne(v);
  } else if (i < 909376) {
    int oc = i - 909312;
    float inv = gamma[oc] * rsqrtf(var[oc] + 1e-5f);
    gsh[oc] = beta[oc] - mean[oc] * inv;
  }
}

// ---------------- K1: x -> zero-halo-padded bf16 (half batch) ----------------
// layout [bh][ic][392][392], halo=3. grid (392, 120) block 256.
__global__ __launch_bounds__(256) void k_xpad(
    const float* __restrict__ x, unsigned short* __restrict__ xp, int b0)
{
  const int r = blockIdx.x;          // padded row 0..391
  const int img = blockIdx.y;        // bh*15+ic
  const int bh = img / 15, ic = img % 15;
  unsigned* orow = (unsigned*)(xp + (size_t)img * IPL + (size_t)r * WP);
  const int y = r - 3;
  const int t = threadIdx.x;
  if (y < 0 || y >= HW) {
    for (int i = t; i < 196; i += 256) orow[i] = 0u;
    return;
  }
  const float* xrow = x + ((size_t)(b0 + bh) * CIN + ic) * XPL + (size_t)y * HW;
  for (int i = t; i < 196; i += 256) {
    int s0 = 2 * i - 3, s1 = 2 * i - 2;
    unsigned lo = (s0 >= 0 && s0 < HW) ? bf16rne(xrow[s0]) : 0u;
    unsigned hi = (s1 >= 0 && s1 < HW) ? bf16rne(xrow[s1]) : 0u;
    orow[i] = lo | (hi << 16);
  }
}

// ---------------- MFMA 7x7 conv from padded bf16 (S=2 gating / S=4 expert) ----------------
// Block 16 px x (4*NT) rows, 4 waves; wave owns NT row-tiles, all 64 oc (4 m-tiles).
// A: b128 from W[oc][k960]. B: plain loads from padded bf16 — no masks/perms/cvt.
template<int S, int NT, bool EXP>
__global__ __launch_bounds__(256) void k_conv7p(
    const unsigned short* __restrict__ xp, const unsigned short* __restrict__ Wp,
    const float* __restrict__ biasp, const int* __restrict__ idxb,
    unsigned short* __restrict__ Obuf, int b0)
{
  const int t = threadIdx.x, w = t >> 6, lane = t & 63, q = lane >> 4, ln = lane & 15;
  const int bh = blockIdx.z, b = b0 + bh;
  const int e = EXP ? idxb[b] : 0;
  const unsigned short* W = Wp + e * 61440;
  const float* bs = biasp + (EXP ? e * 64 : 0);
  const int px0 = blockIdx.x * 16, py0 = blockIdx.y * (4 * NT);
  const int px = px0 + ln;
  const int colo = S * px;           // padded col of first tap (halo absorbs -3)

  int rbase[NT];
#pragma unroll
  for (int nt = 0; nt < NT; ++nt) rbase[nt] = S * (py0 + w * NT + nt) + q;
  int aoff[4];
#pragma unroll
  for (int mt = 0; mt < 4; ++mt) aoff[mt] = (mt * 16 + ln) * 960 + q * 8;

  floatx4 acc[4][NT];
#pragma unroll
  for (int mt = 0; mt < 4; ++mt)
#pragma unroll
    for (int nt = 0; nt < NT; ++nt) acc[mt][nt] = 0.f;

#pragma unroll 3
  for (int ic = 0; ic < CIN; ++ic) {
    const unsigned short* icp = xp + (size_t)(bh * CIN + ic) * IPL;
#pragma unroll
    for (int h = 0; h < 2; ++h) {
      short8 af[4];
#pragma unroll
      for (int mt = 0; mt < 4; ++mt)
        af[mt] = *(const short8*)(W + aoff[mt] + ic * 64 + h * 32);
      short8 bf[NT];
#pragma unroll
      for (int nt = 0; nt < NT; ++nt) {
        const unsigned short* p = icp + (rbase[nt] + 4 * h) * WP + colo;
        union { unsigned u[4]; short8 s; } cv;
        if (S == 2) {                 // 4B-aligned
          const unsigned* pu = (const unsigned*)p;
          cv.u[0] = pu[0]; cv.u[1] = pu[1]; cv.u[2] = pu[2]; cv.u[3] = pu[3];
        } else {                      // 8B-aligned
          const uintx2* pu = (const uintx2*)p;
          uintx2 a = pu[0], bq = pu[1];
          cv.u[0] = a.x; cv.u[1] = a.y; cv.u[2] = bq.x; cv.u[3] = bq.y;
        }
        bf[nt] = cv.s;
      }
#pragma unroll
      for (int mt = 0; mt < 4; ++mt)
#pragma unroll
        for (int nt = 0; nt < NT; ++nt)
          acc[mt][nt] = __builtin_amdgcn_mfma_f32_16x16x32_bf16(af[mt], bf[nt], acc[mt][nt], 0, 0, 0);
    }
  }

#pragma unroll
  for (int nt = 0; nt < NT; ++nt) {
    int py = py0 + w * NT + nt;
    size_t rowo;
    if (EXP)  // padded Y1 NHWC [b][py+1][px+1][64]
      rowo = (((size_t)b * YP + py + 1) * YP + px + 1) * 64;
    else      // Cbuf NHWC [bh][py][px][64]
      rowo = (((size_t)bh * GW + py) * GW + px) * 64;
#pragma unroll
    for (int mt = 0; mt < 4; ++mt) {
      int ocb = mt * 16 + q * 4;
      float v0 = fmaxf(acc[mt][nt][0] + bs[ocb + 0], 0.f);
      float v1 = fmaxf(acc[mt][nt][1] + bs[ocb + 1], 0.f);
      float v2 = fmaxf(acc[mt][nt][2] + bs[ocb + 2], 0.f);
      float v3 = fmaxf(acc[mt][nt][3] + bs[ocb + 3], 0.f);
      uintx2 pr;
      pr.x = (bf16rne(v1) << 16) | bf16rne(v0);
      pr.y = (bf16rne(v3) << 16) | bf16rne(v2);
      *(uintx2*)(Obuf + rowo + ocb) = pr;
    }
  }
}

// ---------------- pool(3x3 s2 p1) + mean partial (half batch) ----------------
__global__ __launch_bounds__(256) void k_pool(const unsigned short* __restrict__ Cb,
                                              float* __restrict__ feat, int b0)
{
  const int py = blockIdx.x, bh = blockIdx.y;
  const int t = threadIdx.x, oc = t & 63, strip = t >> 6;
  const unsigned short* base = Cb + (size_t)bh * GW * GW * 64 + oc;
  float sum = 0.f;
  for (int px = strip * 24; px < strip * 24 + 24; ++px) {
    float m = 0.f;
#pragma unroll
    for (int dy = 0; dy < 3; ++dy) {
      int row = 2 * py - 1 + dy;
      if (row < 0 || row >= GW) continue;
#pragma unroll
      for (int dx = 0; dx < 3; ++dx) {
        int col = 2 * px - 1 + dx;
        if (col < 0 || col >= GW) continue;
        m = fmaxf(m, bf2f(base[((size_t)row * GW + col) * 64]));
      }
    }
    sum += m;
  }
  __shared__ float red[4][64];
  red[strip][oc] = sum;
  __syncthreads();
  if (t < 64) {
    float s = red[0][oc] + red[1][oc] + red[2][oc] + red[3][oc];
    atomicAdd(&feat[(b0 + bh) * 64 + oc], s);
  }
}

// ---------------- FC + argmax + aux (feat holds SUMS) ----------------
__global__ __launch_bounds__(64) void k_gate_fc(
    const float* __restrict__ feat, const float* __restrict__ fcw,
    const float* __restrict__ fcb, int* __restrict__ idxb,
    float* __restrict__ out_aux)
{
  __shared__ float sm[16][3];
  __shared__ int sidx[16];
  int t = threadIdx.x;
  if (t < 16) {
    float l[3];
#pragma unroll
    for (int e = 0; e < 3; ++e) {
      float s = fcb[e];
      for (int c = 0; c < 64; ++c)
        s = fmaf(feat[t * 64 + c] * (1.f / 9216.f), fcw[e * 64 + c], s);
      l[e] = s;
    }
    int best = 0; float bv = l[0];
    if (l[1] > bv) { bv = l[1]; best = 1; }
    if (l[2] > bv) { bv = l[2]; best = 2; }
    sidx[t] = best; idxb[t] = best;
    float mx = fmaxf(l[0], fmaxf(l[1], l[2]));
    float e0 = expf(l[0] - mx), e1 = expf(l[1] - mx), e2 = expf(l[2] - mx);
    float d = e0 + e1 + e2;
    sm[t][0] = e0 / d; sm[t][1] = e1 / d; sm[t][2] = e2 / d;
  }
  __syncthreads();
  if (t == 0) {
    float aux = 0.f;
    for (int e = 0; e < 3; ++e) {
      float cnt = 0.f, pr = 0.f;
      for (int b = 0; b < 16; ++b) { cnt += (sidx[b] == e) ? 1.f : 0.f; pr += sm[b][e]; }
      aux += (cnt / 16.f) * (pr / 16.f);
    }
    *out_aux = 0.01f * aux * 3.f;
  }
}

// ---------------- head: 3x3 64->384 MFMA + fused grouped 1x1 (padded Y1) ----------------
__global__ __launch_bounds__(256) void k_headm(
    const unsigned short* __restrict__ Y1, const unsigned short* __restrict__ Whp,
    const float* __restrict__ b1, const float* __restrict__ w2,
    const float* __restrict__ b2, const int* __restrict__ idxb,
    float* __restrict__ out)
{
  const int t = threadIdx.x, w = t >> 6, lane = t & 63, q = lane >> 4, ln = lane & 15;
  const int b = blockIdx.z, px0 = blockIdx.x * 16, py0 = blockIdx.y * 4;
  const int e = idxb[b];
  const unsigned short* W = Whp + e * 221184;
  const int px = px0 + ln;

  int aoff[6];
#pragma unroll
  for (int mt = 0; mt < 6; ++mt) aoff[mt] = (w * 96 + mt * 16 + ln) * 576 + q * 8;

  int bbase[4];
#pragma unroll
  for (int nt = 0; nt < 4; ++nt)
    bbase[nt] = ((b * YP + py0 + nt) * YP + px) * 64 + q * 8;

  floatx4 acc[6][4];
#pragma unroll
  for (int mt = 0; mt < 6; ++mt)
#pragma unroll
    for (int nt = 0; nt < 4; ++nt) acc[mt][nt] = 0.f;

#pragma unroll
  for (int kk = 0; kk < 9; ++kk) {
    const int ky = kk / 3, kx = kk % 3;
#pragma unroll
    for (int ih = 0; ih < 2; ++ih) {
      const int stepc = (ky * YP + kx) * 64 + ih * 32;
      short8 bf[4];
#pragma unroll
      for (int nt = 0; nt < 4; ++nt) {
        union { uintx4 u; short8 s; } cv;
        cv.u = *(const uintx4*)(Y1 + bbase[nt] + stepc);
        bf[nt] = cv.s;
      }
      const int kOff = kk * 64 + ih * 32;
#pragma unroll
      for (int mt = 0; mt < 6; ++mt) {
        short8 af = *(const short8*)(W + aoff[mt] + kOff);
#pragma unroll
        for (int nt = 0; nt < 4; ++nt)
          acc[mt][nt] = __builtin_amdgcn_mfma_f32_16x16x32_bf16(af, bf[nt], acc[mt][nt], 0, 0, 0);
      }
    }
  }

  __shared__ float sred[4][4][16][6];
#pragma unroll
  for (int nt = 0; nt < 4; ++nt) {
    float part[6] = {0.f, 0.f, 0.f, 0.f, 0.f, 0.f};
#pragma unroll
    for (int mt = 0; mt < 6; ++mt) {
      int ocb = w * 96 + mt * 16 + q * 4;
#pragma unroll
      for (int r = 0; r < 4; ++r) {
        int oc = ocb + r;
        float y = fmaxf(acc[mt][nt][r] + b1[e * 384 + oc], 0.f);
        int g = oc >> 7, kb = oc & 127;
        part[2 * g]     += y * w2[(e * 6 + 2 * g) * 128 + kb];
        part[2 * g + 1] += y * w2[(e * 6 + 2 * g + 1) * 128 + kb];
      }
    }
#pragma unroll
    for (int c = 0; c < 6; ++c) {
      part[c] += __shfl_down(part[c], 32);
      part[c] += __shfl_down(part[c], 16);
    }
    if (q == 0) {
#pragma unroll
      for (int c = 0; c < 6; ++c) sred[nt][w][ln][c] = part[c];
    }
  }
  __syncthreads();
  for (int i = t; i < 384; i += 256) {
    int pix = i / 6, c = i % 6;
    int nt = pix >> 4, pl = pix & 15;
    float s = sred[nt][0][pl][c] + sred[nt][1][pl][c] + sred[nt][2][pl][c] +
              sred[nt][3][pl][c] + b2[e * 6 + c];
    out[(((size_t)(b * 6 + c)) * PH + (py0 + nt)) * PH + (px0 + pl)] = s;
  }
}

// ---------------- launch ----------------
extern "C" void kernel_launch(void* const* d_in, const int* in_sizes, int n_in,
                              void* d_out, int out_size, void* d_ws, size_t ws_size,
                              hipStream_t stream)
{
  const float* x         = (const float*)d_in[0];
  const float* g_fc_w    = (const float*)d_in[6];
  const float* g_fc_b    = (const float*)d_in[7];
  const float* e_conv1_b = (const float*)d_in[9];
  const float* e_head_b1 = (const float*)d_in[11];
  const float* e_head_w2 = (const float*)d_in[12];
  const float* e_head_b2 = (const float*)d_in[13];

  unsigned char* wsb = (unsigned char*)d_ws;
  unsigned short* Wg  = (unsigned short*)(wsb + OFF_WG);
  unsigned short* We1 = (unsigned short*)(wsb + OFF_WE1);
  unsigned short* Wh  = (unsigned short*)(wsb + OFF_WH);
  float* gsh  = (float*)(wsb + OFF_GSH);
  float* feat = (float*)(wsb + OFF_FEAT);
  int*   idxb = (int*)(wsb + OFF_IDX);
  unsigned short* xpad = (unsigned short*)(wsb + OFF_XPAD);
  unsigned short* Cbuf = (unsigned short*)(wsb + OFF_CBUF);
  unsigned short* Y1   = (unsigned short*)(wsb + OFF_CBUF);   // overlays Cbuf

  float* out = (float*)d_out;
  float* out_aux = out + OUT_ELEMS;

  hipMemsetAsync(feat, 0, 16 * 64 * sizeof(float), stream);
  hipLaunchKernelGGL(k_prep, dim3(3553), dim3(256), 0, stream,
                     (const float*)d_in[1], (const float*)d_in[8], (const float*)d_in[10],
                     (const float*)d_in[2], (const float*)d_in[5],
                     (const float*)d_in[3], (const float*)d_in[4], wsb);

  // gating, half 0 then half 1
  hipLaunchKernelGGL(k_xpad, dim3(392, 120), dim3(256), 0, stream, x, xpad, 0);
  hipLaunchKernelGGL((k_conv7p<2, 4, false>), dim3(12, 12, 8), dim3(256), 0, stream,
                     xpad, Wg, gsh, idxb, Cbuf, 0);
  hipLaunchKernelGGL(k_pool, dim3(96, 8), dim3(256), 0, stream, Cbuf, feat, 0);
  hipLaunchKernelGGL(k_xpad, dim3(392, 120), dim3(256), 0, stream, x, xpad, 8);
  hipLaunchKernelGGL((k_conv7p<2, 4, false>), dim3(12, 12, 8), dim3(256), 0, stream,
                     xpad, Wg, gsh, idxb, Cbuf, 8);
  hipLaunchKernelGGL(k_pool, dim3(96, 8), dim3(256), 0, stream, Cbuf, feat, 8);
  hipLaunchKernelGGL(k_gate_fc, dim3(1), dim3(64), 0, stream,
                     feat, g_fc_w, g_fc_b, idxb, out_aux);

  // expert conv1 -> padded Y1 (zero halo via memset); xpad currently holds half 1
  hipMemsetAsync(Y1, 0, (size_t)16 * Y1IPL * 2, stream);
  hipLaunchKernelGGL((k_conv7p<4, 2, true>), dim3(6, 12, 8), dim3(256), 0, stream,
                     xpad, We1, e_conv1_b, idxb, Y1, 8);
  hipLaunchKernelGGL(k_xpad, dim3(392, 120), dim3(256), 0, stream, x, xpad, 0);
  hipLaunchKernelGGL((k_conv7p<4, 2, true>), dim3(6, 12, 8), dim3(256), 0, stream,
                     xpad, We1, e_conv1_b, idxb, Y1, 0);

  hipLaunchKernelGGL(k_headm, dim3(6, 24, 16), dim3(256), 0, stream,
                     Y1, Wh, e_head_b1, e_head_w2, e_head_b2, idxb, out);
}

// Round 4
// 806.731 us; speedup vs baseline: 1.2586x; 1.2586x over previous
//
#include <hip/hip_runtime.h>
#include <math.h>

// ---------------- problem constants ----------------
#define BB 16
#define CIN 15
#define HW 384
#define XPL 147456             // 384*384
#define NX 35389440            // 16*15*384*384
#define PH 96
#define GW 192
#define YP 98                  // padded Y1 spatial
#define Y1IPL (98*98*64)       // 614656 elems per image
#define OUT_ELEMS (BB*6*PH*PH)

// ws byte offsets (end = 77,594,624 == proven available)
#define OFF_WG   0             // frag-major [30][4][64][8] bf16 (BN-folded)
#define OFF_WE1  122880        // frag-major [3][30][4][64][8] bf16
#define OFF_WH   491520        // frag-major [3][18][24][64][8] bf16
#define OFF_GSH  1818624       // fp32 [64]
#define OFF_FEAT 1818880       // fp32 [16][64]
#define OFF_IDX  1822976       // int  [16]
#define OFF_CBUF 2097152       // bf16 [16][192][192][64] = 75,497,472 B; Y1 overlays

typedef __attribute__((ext_vector_type(8))) short short8;
typedef __attribute__((ext_vector_type(4))) float floatx4;
typedef __attribute__((ext_vector_type(4))) unsigned int uintx4;
typedef __attribute__((ext_vector_type(2))) unsigned int uintx2;

__device__ __forceinline__ unsigned bf16rne(float f) {
  unsigned u = __float_as_uint(f);
  unsigned r = ((u >> 16) & 1u) + 0x7FFFu;
  return (u + r) >> 16;
}
__device__ __forceinline__ float bf2f(unsigned short s) {
  return __uint_as_float(((unsigned)s) << 16);
}

// ---------------- K0: weight prep (fragment-major) ----------------
// Wg/We1: idx = ((ic*2+h)*4 + mt)*512 + lane*8 + j ; oc = mt*16+(lane&15),
//         ky = 4h+(lane>>4), kx = j  (ky==7 or kx==7 -> 0). Wg is BN-folded.
// Wh: idx = ((kk*2+ih)*24 + mt)*512 + lane*8 + j ; oc = mt*16+(lane&15),
//     ic = ih*32+(lane>>4)*8+j.
__global__ __launch_bounds__(256) void k_prep(
    const float* __restrict__ g_conv_w, const float* __restrict__ e_conv1_w,
    const float* __restrict__ e_head_w1,
    const float* __restrict__ gamma, const float* __restrict__ var,
    const float* __restrict__ beta,  const float* __restrict__ mean,
    unsigned char* __restrict__ wsb)
{
  int i = blockIdx.x * 256 + threadIdx.x;
  unsigned short* Wg  = (unsigned short*)(wsb + OFF_WG);
  unsigned short* We1 = (unsigned short*)(wsb + OFF_WE1);
  unsigned short* Wh  = (unsigned short*)(wsb + OFF_WH);
  float* gsh = (float*)(wsb + OFF_GSH);
  if (i < 61440) {
    int j = i & 7, lane = (i >> 3) & 63, mtc = i >> 9;
    int mt = mtc & 3, c = mtc >> 2, ic = c >> 1, h = c & 1;
    int oc = mt * 16 + (lane & 15), q = lane >> 4;
    int ky = 4 * h + q, kx = j;
    float v = 0.f;
    if (ky < 7 && kx < 7) v = g_conv_w[oc * 735 + ic * 49 + ky * 7 + kx];
    float inv = gamma[oc] * rsqrtf(var[oc] + 1e-5f);
    Wg[i] = (unsigned short)bf16rne(v * inv);
  } else if (i < 245760) {
    int r = i - 61440;
    int e = r / 61440, r2 = r % 61440;
    int j = r2 & 7, lane = (r2 >> 3) & 63, mtc = r2 >> 9;
    int mt = mtc & 3, c = mtc >> 2, ic = c >> 1, h = c & 1;
    int oc = mt * 16 + (lane & 15), q = lane >> 4;
    int ky = 4 * h + q, kx = j;
    float v = 0.f;
    if (ky < 7 && kx < 7) v = e_conv1_w[(e * 64 + oc) * 735 + ic * 49 + ky * 7 + kx];
    We1[r] = (unsigned short)bf16rne(v);
  } else if (i < 909312) {
    int r = i - 245760;
    int e = r / 221184, r2 = r % 221184;
    int j = r2 & 7, lane = (r2 >> 3) & 63, mtc = r2 >> 9;
    int mt = mtc % 24, chunk = mtc / 24;
    int kk = chunk >> 1, ih = chunk & 1;
    int oc = mt * 16 + (lane & 15), q = lane >> 4;
    int ic = ih * 32 + q * 8 + j;
    Wh[r] = (unsigned short)bf16rne(e_head_w1[((e * 384 + oc) * 64 + ic) * 9 + kk]);
  } else if (i < 909376) {
    int oc = i - 909312;
    float inv = gamma[oc] * rsqrtf(var[oc] + 1e-5f);
    gsh[oc] = beta[oc] - mean[oc] * inv;
  }
}

// ---------------- K1: gating conv 7x7 s2 via LDS-staged tile ----------------
// grid (12,12,16) block 256 (4 waves). 16x16 out tile; wave w rows w*4..w*4+3.
// LDS: bf16 tile [15][38][38] (row = 19 dwords). Single sync, then pure
// ds_read + coalesced frag-major A + MFMA. Epilogue: BN shift + relu -> Cbuf NHWC.
__global__ __launch_bounds__(256) void k_gconv(
    const float* __restrict__ x, const unsigned short* __restrict__ Wg,
    const float* __restrict__ gsh, unsigned short* __restrict__ Cbuf)
{
  const int t = threadIdx.x, w = t >> 6, lane = t & 63, q = lane >> 4, ln = lane & 15;
  const int bx = blockIdx.x, by = blockIdx.y, b = blockIdx.z;
  const int px0 = bx * 16, py0 = by * 16;
  const int iy0 = 2 * py0 - 3, ix0 = 2 * px0 - 3;

  __shared__ __align__(16) unsigned short tile[21660];  // 15*38*38
  unsigned* tilU = (unsigned*)tile;

  // stage: pairs of columns -> one u32 LDS write. 10830 dwords.
  for (int p = t; p < 10830; p += 256) {
    int ic = p / 722;
    int r2 = p - ic * 722;
    int rr = r2 / 19, cp = r2 - rr * 19;
    int iy = iy0 + rr, ix = ix0 + 2 * cp;
    const float* xr = x + ((size_t)(b * CIN + ic)) * XPL + (size_t)iy * HW;
    bool rok = (iy >= 0) && (iy < HW);
    float v0 = (rok && ix >= 0 && ix < HW) ? xr[ix] : 0.f;
    float v1 = (rok && ix + 1 >= 0 && ix + 1 < HW) ? xr[ix + 1] : 0.f;
    tilU[p] = bf16rne(v0) | (bf16rne(v1) << 16);
  }
  __syncthreads();

  floatx4 acc[4][4];
#pragma unroll
  for (int mt = 0; mt < 4; ++mt)
#pragma unroll
    for (int nt = 0; nt < 4; ++nt) acc[mt][nt] = 0.f;

#pragma unroll 3
  for (int ic = 0; ic < CIN; ++ic) {
#pragma unroll
    for (int h = 0; h < 2; ++h) {
      short8 af[4];
#pragma unroll
      for (int mt = 0; mt < 4; ++mt)
        af[mt] = *(const short8*)(Wg + (((ic * 2 + h) * 4 + mt) << 9) + lane * 8);
      short8 bf[4];
#pragma unroll
      for (int nt = 0; nt < 4; ++nt) {
        int row = 2 * (w * 4 + nt) + 4 * h + q;
        int bd = ic * 722 + row * 19 + ln;
        union { unsigned u[4]; short8 s; } cv;
        cv.u[0] = tilU[bd]; cv.u[1] = tilU[bd + 1];
        cv.u[2] = tilU[bd + 2]; cv.u[3] = tilU[bd + 3];
        bf[nt] = cv.s;
      }
#pragma unroll
      for (int mt = 0; mt < 4; ++mt)
#pragma unroll
        for (int nt = 0; nt < 4; ++nt)
          acc[mt][nt] = __builtin_amdgcn_mfma_f32_16x16x32_bf16(af[mt], bf[nt], acc[mt][nt], 0, 0, 0);
    }
  }

#pragma unroll
  for (int nt = 0; nt < 4; ++nt) {
    int py = py0 + w * 4 + nt, px = px0 + ln;
    size_t rowo = (((size_t)b * GW + py) * GW + px) * 64;
#pragma unroll
    for (int mt = 0; mt < 4; ++mt) {
      int ocb = mt * 16 + q * 4;
      float v0 = fmaxf(acc[mt][nt][0] + gsh[ocb + 0], 0.f);
      float v1 = fmaxf(acc[mt][nt][1] + gsh[ocb + 1], 0.f);
      float v2 = fmaxf(acc[mt][nt][2] + gsh[ocb + 2], 0.f);
      float v3 = fmaxf(acc[mt][nt][3] + gsh[ocb + 3], 0.f);
      uintx2 pr;
      pr.x = (bf16rne(v1) << 16) | bf16rne(v0);
      pr.y = (bf16rne(v3) << 16) | bf16rne(v2);
      *(uintx2*)(Cbuf + rowo + ocb) = pr;
    }
  }
}

// ---------------- pool(3x3 s2 p1) + mean partial (full batch) ----------------
__global__ __launch_bounds__(256) void k_pool(const unsigned short* __restrict__ Cb,
                                              float* __restrict__ feat)
{
  const int py = blockIdx.x, b = blockIdx.y;
  const int t = threadIdx.x, oc = t & 63, strip = t >> 6;
  const unsigned short* base = Cb + (size_t)b * GW * GW * 64 + oc;
  float sum = 0.f;
  for (int px = strip * 24; px < strip * 24 + 24; ++px) {
    float m = 0.f;
#pragma unroll
    for (int dy = 0; dy < 3; ++dy) {
      int row = 2 * py - 1 + dy;
      if (row < 0 || row >= GW) continue;
#pragma unroll
      for (int dx = 0; dx < 3; ++dx) {
        int col = 2 * px - 1 + dx;
        if (col < 0 || col >= GW) continue;
        m = fmaxf(m, bf2f(base[((size_t)row * GW + col) * 64]));
      }
    }
    sum += m;
  }
  __shared__ float red[4][64];
  red[strip][oc] = sum;
  __syncthreads();
  if (t < 64) {
    float s = red[0][oc] + red[1][oc] + red[2][oc] + red[3][oc];
    atomicAdd(&feat[b * 64 + oc], s);
  }
}

// ---------------- FC + argmax + aux (feat holds SUMS) ----------------
__global__ __launch_bounds__(64) void k_gate_fc(
    const float* __restrict__ feat, const float* __restrict__ fcw,
    const float* __restrict__ fcb, int* __restrict__ idxb,
    float* __restrict__ out_aux)
{
  __shared__ float sm[16][3];
  __shared__ int sidx[16];
  int t = threadIdx.x;
  if (t < 16) {
    float l[3];
#pragma unroll
    for (int e = 0; e < 3; ++e) {
      float s = fcb[e];
      for (int c = 0; c < 64; ++c)
        s = fmaf(feat[t * 64 + c] * (1.f / 9216.f), fcw[e * 64 + c], s);
      l[e] = s;
    }
    int best = 0; float bv = l[0];
    if (l[1] > bv) { bv = l[1]; best = 1; }
    if (l[2] > bv) { bv = l[2]; best = 2; }
    sidx[t] = best; idxb[t] = best;
    float mx = fmaxf(l[0], fmaxf(l[1], l[2]));
    float e0 = expf(l[0] - mx), e1 = expf(l[1] - mx), e2 = expf(l[2] - mx);
    float d = e0 + e1 + e2;
    sm[t][0] = e0 / d; sm[t][1] = e1 / d; sm[t][2] = e2 / d;
  }
  __syncthreads();
  if (t == 0) {
    float aux = 0.f;
    for (int e = 0; e < 3; ++e) {
      float cnt = 0.f, pr = 0.f;
      for (int b = 0; b < 16; ++b) { cnt += (sidx[b] == e) ? 1.f : 0.f; pr += sm[b][e]; }
      aux += (cnt / 16.f) * (pr / 16.f);
    }
    *out_aux = 0.01f * aux * 3.f;
  }
}

// ---------------- K4: expert conv1 7x7 s4 (in-register im2col, frag-major A) ----------------
// grid (6,6,16) block 256; 16x16 out tile; wave w rows w*4..w*4+3. Writes padded Y1.
__global__ __launch_bounds__(256) void k_econv(
    const float* __restrict__ x, const unsigned short* __restrict__ We1,
    const float* __restrict__ biasp, const int* __restrict__ idxb,
    unsigned short* __restrict__ Y1)
{
  const int t = threadIdx.x, w = t >> 6, lane = t & 63, q = lane >> 4, ln = lane & 15;
  const int b = blockIdx.z;
  const int e = idxb[b];
  const unsigned short* W = We1 + e * 61440;
  const float* bs = biasp + e * 64;
  const int px0 = blockIdx.x * 16, py0 = blockIdx.y * 16;
  const int px = px0 + ln;

  const int c0 = 4 * px - 3;         // first tap col (c0 & 3 == 1 always)
  const int acol = c0 - 1;           // 16B-aligned col base
  unsigned pm[4];
#pragma unroll
  for (int j = 0; j < 4; ++j) {
    int t0 = 2 * j, t1 = 2 * j + 1;
    unsigned m0 = (c0 + t0 >= 0 && c0 + t0 < HW) ? 0x0000FFFFu : 0u;
    unsigned m1 = (c0 + t1 >= 0 && c0 + t1 < HW) ? 0xFFFF0000u : 0u;
    pm[j] = m0 | m1;
  }

  int syq[4];
#pragma unroll
  for (int nt = 0; nt < 4; ++nt) syq[nt] = 4 * (py0 + w * 4 + nt) + q - 3;
  const int xbase = b * CIN * XPL;

  floatx4 acc[4][4];
#pragma unroll
  for (int mt = 0; mt < 4; ++mt)
#pragma unroll
    for (int nt = 0; nt < 4; ++nt) acc[mt][nt] = 0.f;

#pragma unroll 3
  for (int ic = 0; ic < CIN; ++ic) {
    const int icb = xbase + ic * XPL;
#pragma unroll
    for (int h = 0; h < 2; ++h) {
      short8 af[4];
#pragma unroll
      for (int mt = 0; mt < 4; ++mt)
        af[mt] = *(const short8*)(W + (((ic * 2 + h) * 4 + mt) << 9) + lane * 8);
      short8 bf[4];
#pragma unroll
      for (int nt = 0; nt < 4; ++nt) {
        int iy = syq[nt] + 4 * h;
        bool rv = (iy >= 0) && (iy < HW) && ((4 * h + q) < 7);
        int a0 = icb + iy * HW + acol;
        a0 = max(a0, 0); a0 = min(a0, NX - 12);
        const float* fp = x + a0;
        floatx4 fA = *(const floatx4*)(fp);
        floatx4 fB = *(const floatx4*)(fp + 4);
        floatx4 fC = *(const floatx4*)(fp + 8);
        float g[8];
        g[0] = fA.y; g[1] = fA.z; g[2] = fA.w; g[3] = fB.x;
        g[4] = fB.y; g[5] = fB.z; g[6] = fB.w; g[7] = fC.x;
        union { unsigned u[4]; short8 s; } cv;
#pragma unroll
        for (int j = 0; j < 4; ++j) {
          unsigned p = __builtin_amdgcn_perm(__float_as_uint(g[2 * j + 1]),
                                             __float_as_uint(g[2 * j]), 0x07060302u);
          p &= pm[j];
          cv.u[j] = rv ? p : 0u;
        }
        bf[nt] = cv.s;
      }
#pragma unroll
      for (int mt = 0; mt < 4; ++mt)
#pragma unroll
        for (int nt = 0; nt < 4; ++nt)
          acc[mt][nt] = __builtin_amdgcn_mfma_f32_16x16x32_bf16(af[mt], bf[nt], acc[mt][nt], 0, 0, 0);
    }
  }

#pragma unroll
  for (int nt = 0; nt < 4; ++nt) {
    int py = py0 + w * 4 + nt;
    size_t rowo = (((size_t)b * YP + py + 1) * YP + px + 1) * 64;
#pragma unroll
    for (int mt = 0; mt < 4; ++mt) {
      int ocb = mt * 16 + q * 4;
      float v0 = fmaxf(acc[mt][nt][0] + bs[ocb + 0], 0.f);
      float v1 = fmaxf(acc[mt][nt][1] + bs[ocb + 1], 0.f);
      float v2 = fmaxf(acc[mt][nt][2] + bs[ocb + 2], 0.f);
      float v3 = fmaxf(acc[mt][nt][3] + bs[ocb + 3], 0.f);
      uintx2 pr;
      pr.x = (bf16rne(v1) << 16) | bf16rne(v0);
      pr.y = (bf16rne(v3) << 16) | bf16rne(v2);
      *(uintx2*)(Y1 + rowo + ocb) = pr;
    }
  }
}

// ---------------- head: 3x3 64->384 MFMA (frag-major A) + fused grouped 1x1 ----------------
__global__ __launch_bounds__(256) void k_headm(
    const unsigned short* __restrict__ Y1, const unsigned short* __restrict__ Whp,
    const float* __restrict__ b1, const float* __restrict__ w2,
    const float* __restrict__ b2, const int* __restrict__ idxb,
    float* __restrict__ out)
{
  const int t = threadIdx.x, w = t >> 6, lane = t & 63, q = lane >> 4, ln = lane & 15;
  const int b = blockIdx.z, px0 = blockIdx.x * 16, py0 = blockIdx.y * 4;
  const int e = idxb[b];
  const unsigned short* W = Whp + e * 221184;
  const int px = px0 + ln;

  int bbase[4];
#pragma unroll
  for (int nt = 0; nt < 4; ++nt)
    bbase[nt] = ((b * YP + py0 + nt) * YP + px) * 64 + q * 8;

  floatx4 acc[6][4];
#pragma unroll
  for (int mt = 0; mt < 6; ++mt)
#pragma unroll
    for (int nt = 0; nt < 4; ++nt) acc[mt][nt] = 0.f;

#pragma unroll
  for (int kk = 0; kk < 9; ++kk) {
    const int ky = kk / 3, kx = kk % 3;
#pragma unroll
    for (int ih = 0; ih < 2; ++ih) {
      const int stepc = (ky * YP + kx) * 64 + ih * 32;
      short8 bf[4];
#pragma unroll
      for (int nt = 0; nt < 4; ++nt) {
        union { uintx4 u; short8 s; } cv;
        cv.u = *(const uintx4*)(Y1 + bbase[nt] + stepc);
        bf[nt] = cv.s;
      }
      const int cbase = ((kk * 2 + ih) * 24 + w * 6) << 9;
#pragma unroll
      for (int mt = 0; mt < 6; ++mt) {
        short8 af = *(const short8*)(W + cbase + (mt << 9) + lane * 8);
#pragma unroll
        for (int nt = 0; nt < 4; ++nt)
          acc[mt][nt] = __builtin_amdgcn_mfma_f32_16x16x32_bf16(af, bf[nt], acc[mt][nt], 0, 0, 0);
      }
    }
  }

  __shared__ float sred[4][4][16][6];
#pragma unroll
  for (int nt = 0; nt < 4; ++nt) {
    float part[6] = {0.f, 0.f, 0.f, 0.f, 0.f, 0.f};
#pragma unroll
    for (int mt = 0; mt < 6; ++mt) {
      int ocb = w * 96 + mt * 16 + q * 4;
#pragma unroll
      for (int r = 0; r < 4; ++r) {
        int oc = ocb + r;
        float y = fmaxf(acc[mt][nt][r] + b1[e * 384 + oc], 0.f);
        int g = oc >> 7, kb = oc & 127;
        part[2 * g]     += y * w2[(e * 6 + 2 * g) * 128 + kb];
        part[2 * g + 1] += y * w2[(e * 6 + 2 * g + 1) * 128 + kb];
      }
    }
#pragma unroll
    for (int c = 0; c < 6; ++c) {
      part[c] += __shfl_down(part[c], 32);
      part[c] += __shfl_down(part[c], 16);
    }
    if (q == 0) {
#pragma unroll
      for (int c = 0; c < 6; ++c) sred[nt][w][ln][c] = part[c];
    }
  }
  __syncthreads();
  for (int i = t; i < 384; i += 256) {
    int pix = i / 6, c = i % 6;
    int nt = pix >> 4, pl = pix & 15;
    float s = sred[nt][0][pl][c] + sred[nt][1][pl][c] + sred[nt][2][pl][c] +
              sred[nt][3][pl][c] + b2[e * 6 + c];
    out[(((size_t)(b * 6 + c)) * PH + (py0 + nt)) * PH + (px0 + pl)] = s;
  }
}

// ---------------- launch ----------------
extern "C" void kernel_launch(void* const* d_in, const int* in_sizes, int n_in,
                              void* d_out, int out_size, void* d_ws, size_t ws_size,
                              hipStream_t stream)
{
  const float* x         = (const float*)d_in[0];
  const float* g_fc_w    = (const float*)d_in[6];
  const float* g_fc_b    = (const float*)d_in[7];
  const float* e_conv1_b = (const float*)d_in[9];
  const float* e_head_b1 = (const float*)d_in[11];
  const float* e_head_w2 = (const float*)d_in[12];
  const float* e_head_b2 = (const float*)d_in[13];

  unsigned char* wsb = (unsigned char*)d_ws;
  unsigned short* Wg  = (unsigned short*)(wsb + OFF_WG);
  unsigned short* We1 = (unsigned short*)(wsb + OFF_WE1);
  unsigned short* Wh  = (unsigned short*)(wsb + OFF_WH);
  float* gsh  = (float*)(wsb + OFF_GSH);
  float* feat = (float*)(wsb + OFF_FEAT);
  int*   idxb = (int*)(wsb + OFF_IDX);
  unsigned short* Cbuf = (unsigned short*)(wsb + OFF_CBUF);
  unsigned short* Y1   = (unsigned short*)(wsb + OFF_CBUF);  // overlays Cbuf

  float* out = (float*)d_out;
  float* out_aux = out + OUT_ELEMS;

  hipMemsetAsync(feat, 0, 16 * 64 * sizeof(float), stream);
  hipLaunchKernelGGL(k_prep, dim3(3553), dim3(256), 0, stream,
                     (const float*)d_in[1], (const float*)d_in[8], (const float*)d_in[10],
                     (const float*)d_in[2], (const float*)d_in[5],
                     (const float*)d_in[3], (const float*)d_in[4], wsb);

  hipLaunchKernelGGL(k_gconv, dim3(12, 12, 16), dim3(256), 0, stream,
                     x, Wg, gsh, Cbuf);
  hipLaunchKernelGGL(k_pool, dim3(96, 16), dim3(256), 0, stream, Cbuf, feat);
  hipLaunchKernelGGL(k_gate_fc, dim3(1), dim3(64), 0, stream,
                     feat, g_fc_w, g_fc_b, idxb, out_aux);

  // Y1 overlays Cbuf (consumed by pool); zero for halo, then expert conv fills interior
  hipMemsetAsync(Y1, 0, (size_t)BB * Y1IPL * 2, stream);
  hipLaunchKernelGGL(k_econv, dim3(6, 6, 16), dim3(256), 0, stream,
                     x, We1, e_conv1_b, idxb, Y1);

  hipLaunchKernelGGL(k_headm, dim3(6, 24, 16), dim3(256), 0, stream,
                     Y1, Wh, e_head_b1, e_head_w2, e_head_b2, idxb, out);
}